// Round 11
// baseline (1212.266 us; speedup 1.0000x reference)
//
#include <hip/hip_runtime.h>
#include <hip/hip_bf16.h>

typedef unsigned short ushort_t;
typedef unsigned int uint_t;
typedef unsigned char uchar_t;

typedef __attribute__((ext_vector_type(8))) short bf16x8;
typedef __attribute__((ext_vector_type(4))) float f32x4;
typedef __attribute__((ext_vector_type(2))) float f32x2;

#define NN 20000
#define EE 320000
#define ETOT (EE + NN)
#define NB 768                  // persistent grid: 3 blocks/CU needed, 4/CU capacity
#define NT 256
#define GT (NB * NT)
#define NWAVES (NB * 4)

__device__ __forceinline__ float bf2f(ushort_t u) {
    union { uint_t i; float f; } v; v.i = ((uint_t)u) << 16; return v.f;
}
__device__ __forceinline__ ushort_t f2bf(float f) {
    __hip_bfloat16 h = __float2bfloat16(f);
    ushort_t u; __builtin_memcpy(&u, &h, 2); return u;
}
__device__ __forceinline__ uchar_t f2fp8(float v) {
    int p = __builtin_amdgcn_cvt_pk_fp8_f32(v, v, 0, false);
    return (uchar_t)(p & 0xff);
}
__device__ __forceinline__ float leaky(float v) { return (v > 0.f) ? v : 0.2f * v; }

#define PO_AS1 0
#define PO_AD1 512
#define PO_B1  1024
#define PO_W2  1536
#define PO_AS2 6656
#define PO_AD2 6666
#define PO_B2  6676
#define PTOT   6686

// device-scope sense-reversing grid barrier. bar[0]=cnt, bar[1]=gen (memset 0 pre-launch).
// All NB blocks co-resident (launch_bounds guarantees capacity >= grid).
__device__ __forceinline__ void gridbar(int* bar) {
    __syncthreads();
    if (threadIdx.x == 0) {
        __threadfence();   // release: publish this block's phase writes (wbL2)
        int g = __hip_atomic_load(&bar[1], __ATOMIC_ACQUIRE, __HIP_MEMORY_SCOPE_AGENT);
        int arrived = __hip_atomic_fetch_add(&bar[0], 1, __ATOMIC_ACQ_REL, __HIP_MEMORY_SCOPE_AGENT);
        if (arrived == NB - 1) {
            bar[0] = 0;
            __hip_atomic_fetch_add(&bar[1], 1, __ATOMIC_RELEASE, __HIP_MEMORY_SCOPE_AGENT);
        } else {
            while (__hip_atomic_load(&bar[1], __ATOMIC_ACQUIRE, __HIP_MEMORY_SCOPE_AGENT) == g)
                __builtin_amdgcn_s_sleep(2);
        }
        __threadfence();   // acquire: invalidate L1/L2 so fresh data is fetched
    }
    __syncthreads();
}

__device__ __forceinline__ bool detect_fp32_local(const ushort_t* __restrict__ xa) {
    __shared__ int cnt;
    if (threadIdx.x == 0) cnt = 0;
    __syncthreads();
    int bad = 0;
    for (int i = threadIdx.x; i < 4096; i += 256) {
        float v = bf2f(xa[i]);
        if (!(fabsf(v) < 1e4f)) bad++;
    }
    if (bad) atomicAdd(&cnt, bad);
    __syncthreads();
    return cnt >= 16;
}

__global__ __launch_bounds__(256, 4) void k_fused(
    const void* __restrict__ xraw, const int* __restrict__ ei,
    const int* __restrict__ batch,
    const void* W1, const void* as1, const void* ad1, const void* b1,
    const void* W2, const void* as2, const void* ad2, const void* b2,
    int* bar, float* prm, ushort_t* w1t, uchar_t* h1,
    float* asrcf, float* adstf, float* asrc2f, float* adstf2,
    float* h2, float* out2, int* deg, int* rowptr, int* cursor,
    int* csr_src, int* bsum, void* dout)
{
    __shared__ union {
        ushort_t sA[2048];                       // gemm A-tile (4 KB)
        int wt[4];                               // scan1 wave totals
        int sb[20];                              // scan3 block offsets
        struct { float sm[256]; int lo, hi; } pl; // pool
    } smu;

    int t = threadIdx.x;
    int gid = blockIdx.x * NT + t;
    int wv = t >> 6, lane = t & 63;
    bool isf = detect_fp32_local((const ushort_t*)xraw);

    // ---------------- P0: W1 transpose + params + deg zero ----------------
    for (int idx = gid; idx < 65536; idx += GT) {
        int n = idx & 511, k = idx >> 9;
        float v = isf ? ((const float*)W1)[k * 512 + n]
                      : bf2f(((const ushort_t*)W1)[k * 512 + n]);
        w1t[n * 128 + k] = f2bf(v);
    }
    for (int i = gid; i < PTOT; i += GT) {
        const void* src; int off;
        if (i < 512)       { src = as1; off = i; }
        else if (i < 1024) { src = ad1; off = i - 512; }
        else if (i < 1536) { src = b1;  off = i - 1024; }
        else if (i < 6656) { src = W2;  off = i - 1536; }
        else if (i < 6666) { src = as2; off = i - 6656; }
        else if (i < 6676) { src = ad2; off = i - 6666; }
        else               { src = b2;  off = i - 6676; }
        prm[i] = isf ? ((const float*)src)[off] : bf2f(((const ushort_t*)src)[off]);
    }
    for (int i = gid; i < NN; i += GT) deg[i] = 0;
    gridbar(bar);

    // ---------------- P1: GEMM1 (fp8 h1 + fp32 logits) + hist ----------------
    for (int tb = blockIdx.x; tb < 1250; tb += NB) {
        __syncthreads();                          // protect sA from previous iter
        int m0 = tb * 16;
        {
            ushort_t tmp[8];
            if (isf) {
                const float4* x4 = (const float4*)((const float*)xraw + (size_t)m0 * 128);
                float4 f0 = x4[2 * t], f1 = x4[2 * t + 1];
                tmp[0] = f2bf(f0.x); tmp[1] = f2bf(f0.y); tmp[2] = f2bf(f0.z); tmp[3] = f2bf(f0.w);
                tmp[4] = f2bf(f1.x); tmp[5] = f2bf(f1.y); tmp[6] = f2bf(f1.z); tmp[7] = f2bf(f1.w);
            } else {
                const uint4* x4 = (const uint4*)((const ushort_t*)xraw + (size_t)m0 * 128);
                uint4 u = x4[t];
                __builtin_memcpy(tmp, &u, 16);
            }
            *reinterpret_cast<uint4*>(&smu.sA[t * 8]) = *reinterpret_cast<uint4*>(tmp);
        }
        __syncthreads();
        int mr = lane & 15, quad = lane >> 4;
        int n0 = wv * 128;
        f32x4 acc[8];
#pragma unroll
        for (int ct = 0; ct < 8; ++ct) acc[ct] = {0.f, 0.f, 0.f, 0.f};
#pragma unroll
        for (int kk = 0; kk < 4; ++kk) {
            bf16x8 a = *reinterpret_cast<const bf16x8*>(&smu.sA[mr * 128 + quad * 8 + kk * 32]);
#pragma unroll
            for (int ct = 0; ct < 8; ++ct) {
                bf16x8 bb = *reinterpret_cast<const bf16x8*>(
                    &w1t[(size_t)(n0 + ct * 16 + mr) * 128 + quad * 8 + kk * 32]);
                acc[ct] = __builtin_amdgcn_mfma_f32_16x16x32_bf16(a, bb, acc[ct], 0, 0, 0);
            }
        }
        int col = lane & 15;
#pragma unroll
        for (int hh = 0; hh < 2; ++hh) {
            float Ss[4] = {0.f, 0.f, 0.f, 0.f}, Dd[4] = {0.f, 0.f, 0.f, 0.f};
#pragma unroll
            for (int c4 = 0; c4 < 4; ++c4) {
                int ct = hh * 4 + c4;
                int abscol = n0 + ct * 16 + col;
                float asv = prm[PO_AS1 + abscol];
                float adv = prm[PO_AD1 + abscol];
                float ps[4], pd[4];
#pragma unroll
                for (int r = 0; r < 4; ++r) {
                    h1[(size_t)(m0 + quad * 4 + r) * 512 + abscol] = f2fp8(acc[ct][r]);
                    ps[r] = acc[ct][r] * asv;
                    pd[r] = acc[ct][r] * adv;
                }
#pragma unroll
                for (int off = 1; off <= 8; off <<= 1) {
#pragma unroll
                    for (int r = 0; r < 4; ++r) {
                        ps[r] += __shfl_xor(ps[r], off, 64);
                        pd[r] += __shfl_xor(pd[r], off, 64);
                    }
                }
#pragma unroll
                for (int r = 0; r < 4; ++r) { Ss[r] += ps[r]; Dd[r] += pd[r]; }
            }
            if (col == 0) {
                int head = 2 * wv + hh;
#pragma unroll
                for (int r = 0; r < 4; ++r) {
                    asrcf[(m0 + quad * 4 + r) * 8 + head] = Ss[r];
                    adstf[(m0 + quad * 4 + r) * 8 + head] = Dd[r];
                }
            }
        }
    }
    for (int e = gid; e < ETOT; e += GT) {
        int dst = (e < EE) ? ei[EE + e] : (e - EE);
        atomicAdd(&deg[dst], 1);
    }
    gridbar(bar);

    // ---------------- P2: scan1 (20 partitions x 1000, 4 elems/thread) ----------------
    if (blockIdx.x < 20) {
        int base = blockIdx.x * 1000;
        int d0 = 0, d1 = 0, d2 = 0, d3 = 0, s = 0;
        if (t < 250) {
            d0 = deg[base + 4 * t]; d1 = deg[base + 4 * t + 1];
            d2 = deg[base + 4 * t + 2]; d3 = deg[base + 4 * t + 3];
            s = d0 + d1 + d2 + d3;
        }
        int incl = s;
#pragma unroll
        for (int off = 1; off < 64; off <<= 1) {
            int u = __shfl_up(incl, off, 64);
            if (lane >= off) incl += u;
        }
        if (lane == 63) smu.wt[wv] = incl;
        __syncthreads();
        int woff = 0;
        for (int w = 0; w < 4; ++w) if (w < wv) woff += smu.wt[w];
        int excl = woff + incl - s;
        if (t < 250) {
            rowptr[base + 4 * t + 1] = excl + d0;
            rowptr[base + 4 * t + 2] = excl + d0 + d1;
            rowptr[base + 4 * t + 3] = excl + d0 + d1 + d2;
            rowptr[base + 4 * t + 4] = excl + s;
        }
        if (t == 0) bsum[blockIdx.x] = smu.wt[0] + smu.wt[1] + smu.wt[2] + smu.wt[3];
    }
    gridbar(bar);

    // ---------------- P3: scan3 (block offsets + cursor) ----------------
    if (t < 64) {
        int v = (t < 20) ? bsum[t] : 0;
        int sc = v;
#pragma unroll
        for (int off = 1; off < 32; off <<= 1) {
            int u = __shfl_up(sc, off, 64);
            if (t >= off) sc += u;
        }
        if (t < 20) smu.sb[t] = sc - v;
    }
    __syncthreads();
    for (int i = gid; i < NN; i += GT) {
        int r = rowptr[i + 1] + smu.sb[i / 1000];
        rowptr[i + 1] = r;
        cursor[i] = r - deg[i];
    }
    if (gid == 0) rowptr[0] = 0;
    gridbar(bar);

    // ---------------- P4: scatter ----------------
    for (int e = gid; e < ETOT; e += GT) {
        int src, dst;
        if (e < EE) { src = ei[e]; dst = ei[EE + e]; } else { src = dst = e - EE; }
        int pos = atomicAdd(&cursor[dst], 1);
        csr_src[pos] = src;
    }
    gridbar(bar);

    // ---------------- P5: layer-1 agg + ELU + fused W2 + layer-2 logits (wave/node) ----
    {
        int hh = lane >> 3, cb = lane * 8;
        for (int n = blockIdx.x * 4 + wv; n < NN; n += NWAVES) {
            int start = rowptr[n], end = rowptr[n + 1];
            int dg = end - start;
            float adh = adstf[n * 8 + hh];
            float a0 = 0.f, a1 = 0.f, a2 = 0.f, a3 = 0.f, a4 = 0.f, a5 = 0.f, a6 = 0.f, a7 = 0.f;
            float den = 0.f;
            for (int base = 0; base < dg; base += 64) {
                int m = min(64, dg - base);
                int sIdx = csr_src[start + base + min(lane, m - 1)];
                for (int g = 0; g < m; g += 8) {
                    int s[8]; float lo[8]; uint2 p[8];
#pragma unroll
                    for (int j = 0; j < 8; ++j)
                        s[j] = __shfl(sIdx, min(g + j, m - 1), 64);
#pragma unroll
                    for (int j = 0; j < 8; ++j)
                        lo[j] = asrcf[s[j] * 8 + hh];
#pragma unroll
                    for (int j = 0; j < 8; ++j)
                        p[j] = *reinterpret_cast<const uint2*>(&h1[(size_t)s[j] * 512 + cb]);
#pragma unroll
                    for (int j = 0; j < 8; ++j) {
                        float we = (g + j < m) ? __expf(leaky(lo[j] + adh)) : 0.f;
                        den += we;
                        f32x2 q0 = __builtin_amdgcn_cvt_pk_f32_fp8((int)p[j].x, false);
                        f32x2 q1 = __builtin_amdgcn_cvt_pk_f32_fp8((int)p[j].x, true);
                        f32x2 q2 = __builtin_amdgcn_cvt_pk_f32_fp8((int)p[j].y, false);
                        f32x2 q3 = __builtin_amdgcn_cvt_pk_f32_fp8((int)p[j].y, true);
                        a0 += we * q0.x; a1 += we * q0.y;
                        a2 += we * q1.x; a3 += we * q1.y;
                        a4 += we * q2.x; a5 += we * q2.y;
                        a6 += we * q3.x; a7 += we * q3.y;
                    }
                }
            }
            float inv = 1.f / (den + 1e-16f);
            float r[8] = {a0, a1, a2, a3, a4, a5, a6, a7};
            float p2[10];
#pragma unroll
            for (int c = 0; c < 10; ++c) p2[c] = 0.f;
#pragma unroll
            for (int j = 0; j < 8; ++j) {
                float rv = r[j] * inv + prm[PO_B1 + cb + j];
                rv = (rv > 0.f) ? rv : expm1f(rv);    // ELU
#pragma unroll
                for (int c = 0; c < 10; ++c)
                    p2[c] += rv * prm[PO_W2 + (cb + j) * 10 + c];
            }
#pragma unroll
            for (int c = 0; c < 10; ++c)
#pragma unroll
                for (int off = 32; off; off >>= 1)
                    p2[c] += __shfl_xor(p2[c], off, 64);
            if (lane == 0) {
                float as = 0.f, ad = 0.f;
#pragma unroll
                for (int c = 0; c < 10; ++c) {
                    h2[n * 10 + c] = p2[c];
                    as += p2[c] * prm[PO_AS2 + c];
                    ad += p2[c] * prm[PO_AD2 + c];
                }
                asrc2f[n] = as; adstf2[n] = ad;
            }
        }
    }
    gridbar(bar);

    // ---------------- P6: layer-2 softmax + aggregation (wave/node) ----------------
    for (int n = blockIdx.x * 4 + wv; n < NN; n += NWAVES) {
        int start = rowptr[n], end = rowptr[n + 1];
        float adn = adstf2[n];
        float den = 0.f;
        float oc[10];
#pragma unroll
        for (int c = 0; c < 10; ++c) oc[c] = 0.f;
        int e = start + lane;
        int s_cur = (e < end) ? csr_src[e] : 0;
        for (; e < end; ) {
            int e_next = e + 64;
            int s_next = (e_next < end) ? csr_src[e_next] : 0;
            float lo = asrc2f[s_cur];
            const float2* hp = reinterpret_cast<const float2*>(&h2[s_cur * 10]);
            float2 q0 = hp[0], q1 = hp[1], q2 = hp[2], q3 = hp[3], q4 = hp[4];
            float ee = __expf(leaky(lo + adn));
            den += ee;
            oc[0] += ee * q0.x; oc[1] += ee * q0.y;
            oc[2] += ee * q1.x; oc[3] += ee * q1.y;
            oc[4] += ee * q2.x; oc[5] += ee * q2.y;
            oc[6] += ee * q3.x; oc[7] += ee * q3.y;
            oc[8] += ee * q4.x; oc[9] += ee * q4.y;
            e = e_next; s_cur = s_next;
        }
#pragma unroll
        for (int off = 32; off; off >>= 1) {
            den += __shfl_xor(den, off, 64);
#pragma unroll
            for (int c = 0; c < 10; ++c) oc[c] += __shfl_xor(oc[c], off, 64);
        }
        if (lane == 0) {
            float inv = 1.f / (den + 1e-16f);
            for (int c = 0; c < 10; ++c) out2[n * 10 + c] = oc[c] * inv + prm[PO_B2 + c];
        }
    }
    gridbar(bar);

    // ---------------- P7: per-graph mean pool (blocks 0..63) ----------------
    if (blockIdx.x < 64) {
        int g = blockIdx.x;
        if (t == 0) {
            int lo = 0, hi = NN;
            while (lo < hi) { int mid = (lo + hi) >> 1; if (batch[mid] < g) lo = mid + 1; else hi = mid; }
            smu.pl.lo = lo;
            int lo2 = lo, hi2 = NN;
            while (lo2 < hi2) { int mid = (lo2 + hi2) >> 1; if (batch[mid] < g + 1) lo2 = mid + 1; else hi2 = mid; }
            smu.pl.hi = lo2;
        }
        __syncthreads();
        int lo = smu.pl.lo, hi = smu.pl.hi;
        float acc[10];
#pragma unroll
        for (int c = 0; c < 10; ++c) acc[c] = 0.f;
        for (int i = lo + t; i < hi; i += 256)
#pragma unroll
            for (int c = 0; c < 10; ++c) acc[c] += out2[i * 10 + c];
        float cnt = (float)((hi - lo) > 0 ? (hi - lo) : 1);
        for (int c = 0; c < 10; ++c) {
            smu.pl.sm[t] = acc[c]; __syncthreads();
            for (int off = 128; off; off >>= 1) {
                if (t < off) smu.pl.sm[t] += smu.pl.sm[t + off];
                __syncthreads();
            }
            if (t == 0) {
                float r = smu.pl.sm[0] / cnt;
                if (isf) ((float*)dout)[g * 10 + c] = r;
                else     ((ushort_t*)dout)[g * 10 + c] = f2bf(r);
            }
            __syncthreads();
        }
    }
}

extern "C" void kernel_launch(void* const* d_in, const int* in_sizes, int n_in,
                              void* d_out, int out_size, void* d_ws, size_t ws_size,
                              hipStream_t stream) {
    const void* x   = d_in[0];
    const int* ei   = (const int*)d_in[1];
    const int* batch= (const int*)d_in[2];
    const void* W1  = d_in[3];
    const void* as1 = d_in[4];
    const void* ad1 = d_in[5];
    const void* b1  = d_in[6];
    const void* W2  = d_in[7];
    const void* as2 = d_in[8];
    const void* ad2 = d_in[9];
    const void* b2  = d_in[10];

    char* p = (char*)d_ws;
    auto alloc = [&](size_t bytes) {
        char* r = p; p += (bytes + 255) & ~(size_t)255; return r;
    };
    int* bar        = (int*)alloc(256);
    float* prm      = (float*)alloc((size_t)PTOT * 4);
    ushort_t* w1t   = (ushort_t*)alloc(512 * 128 * 2);
    uchar_t* h1     = (uchar_t*)alloc((size_t)NN * 512);          // 10.24 MB fp8
    float* asrc1f   = (float*)alloc((size_t)NN * 8 * 4);
    float* adst1f   = (float*)alloc((size_t)NN * 8 * 4);
    float* asrc2f   = (float*)alloc((size_t)NN * 4);
    float* adst2f   = (float*)alloc((size_t)NN * 4);
    float* h2       = (float*)alloc((size_t)NN * 10 * 4);
    float* out2     = (float*)alloc((size_t)NN * 10 * 4);
    int* deg        = (int*)alloc((size_t)NN * 4);
    int* rowptr     = (int*)alloc((size_t)(NN + 1) * 4);
    int* cursor     = (int*)alloc((size_t)NN * 4);
    int* csr_src    = (int*)alloc((size_t)ETOT * 4);
    int* bsum       = (int*)alloc(32 * 4);

    hipMemsetAsync(bar, 0, 16, stream);
    k_fused<<<NB, NT, 0, stream>>>(x, ei, batch, W1, as1, ad1, b1, W2, as2, ad2, b2,
                                   bar, prm, w1t, h1, asrc1f, adst1f, asrc2f, adst2f,
                                   h2, out2, deg, rowptr, cursor, csr_src, bsum, d_out);
}

// Round 12
// 265.199 us; speedup vs baseline: 4.5712x; 4.5712x over previous
//
#include <hip/hip_runtime.h>
#include <hip/hip_bf16.h>

typedef unsigned short ushort_t;
typedef unsigned int uint_t;
typedef unsigned char uchar_t;

typedef __attribute__((ext_vector_type(8))) short bf16x8;
typedef __attribute__((ext_vector_type(4))) float f32x4;
typedef __attribute__((ext_vector_type(2))) float f32x2;

__device__ __forceinline__ float bf2f(ushort_t u) {
    union { uint_t i; float f; } v; v.i = ((uint_t)u) << 16; return v.f;
}
__device__ __forceinline__ ushort_t f2bf(float f) {
    __hip_bfloat16 h = __float2bfloat16(f);
    ushort_t u; __builtin_memcpy(&u, &h, 2); return u;
}
__device__ __forceinline__ uchar_t f2fp8(float v) {
    int p = __builtin_amdgcn_cvt_pk_fp8_f32(v, v, 0, false);
    return (uchar_t)(p & 0xff);
}
__device__ __forceinline__ float leaky(float v) { return (v > 0.f) ? v : 0.2f * v; }

#define PO_AS1 0
#define PO_AD1 512
#define PO_B1  1024
#define PO_W2  1536
#define PO_AS2 6656
#define PO_AD2 6666
#define PO_B2  6676
#define PTOT   6686

// block-local fp32-vs-bf16 probe on x (first 4096 ushorts).
__device__ __forceinline__ bool detect_fp32_local(const ushort_t* __restrict__ xa) {
    __shared__ int cnt;
    if (threadIdx.x == 0) cnt = 0;
    __syncthreads();
    int bad = 0;
    for (int i = threadIdx.x; i < 4096; i += 256) {
        float v = bf2f(xa[i]);
        if (!(fabsf(v) < 1e4f)) bad++;
    }
    if (bad) atomicAdd(&cnt, bad);
    __syncthreads();
    return cnt >= 16;
}

// ---- prep: W1 transpose + param normalize + deg zero ----
__global__ __launch_bounds__(256) void k_prep(const void* __restrict__ x,
                                              const void* __restrict__ W1,
                                              const void* as1, const void* ad1,
                                              const void* b1, const void* W2,
                                              const void* as2, const void* ad2,
                                              const void* b2,
                                              ushort_t* __restrict__ W1t,
                                              float* __restrict__ prm,
                                              int* __restrict__ deg, int N) {
    int b = blockIdx.x, t = threadIdx.x;
    if (b < 283) {
        bool isf = detect_fp32_local((const ushort_t*)x);
        if (b < 256) {
            int idx = b * 256 + t;
            int n = idx & 511, k = idx >> 9;
            float v = isf ? ((const float*)W1)[k * 512 + n]
                          : bf2f(((const ushort_t*)W1)[k * 512 + n]);
            W1t[n * 128 + k] = f2bf(v);
        } else {
            int i = (b - 256) * 256 + t;
            if (i < PTOT) {
                const void* src; int off;
                if (i < 512)       { src = as1; off = i; }
                else if (i < 1024) { src = ad1; off = i - 512; }
                else if (i < 1536) { src = b1;  off = i - 1024; }
                else if (i < 6656) { src = W2;  off = i - 1536; }
                else if (i < 6666) { src = as2; off = i - 6656; }
                else if (i < 6676) { src = ad2; off = i - 6666; }
                else               { src = b2;  off = i - 6676; }
                prm[i] = isf ? ((const float*)src)[off] : bf2f(((const ushort_t*)src)[off]);
            }
        }
    } else {
        int i = (b - 283) * 256 + t;
        if (i < N) deg[i] = 0;
    }
}

// ------ fused GEMM1 (+logits) and degree histogram (independent halves) ------
// blocks [0,1250): gemm tile; blocks [1250, 1250+ceil(Etot/256)): histogram
__global__ __launch_bounds__(256) void k_gemm_hist(const void* __restrict__ xraw,
                                                   const ushort_t* __restrict__ w1t,
                                                   const float* __restrict__ prm,
                                                   const int* __restrict__ ei,
                                                   uchar_t* __restrict__ h1,
                                                   float* __restrict__ asrcf,
                                                   float* __restrict__ adstf,
                                                   int* __restrict__ deg,
                                                   int E, int Etot) {
    int b = blockIdx.x, t = threadIdx.x;
    if (b >= 1250) {
        int e = (b - 1250) * 256 + t;
        if (e < Etot) {
            int dst = (e < E) ? ei[E + e] : (e - E);
            atomicAdd(&deg[dst], 1);
        }
        return;
    }
    int wave = t >> 6, lane = t & 63;
    int m0 = b * 16;
    bool isf = detect_fp32_local((const ushort_t*)xraw);
    __shared__ ushort_t sA[16 * 128];
    {
        ushort_t tmp[8];
        if (isf) {
            const float4* x4 = (const float4*)((const float*)xraw + (size_t)m0 * 128);
            float4 f0 = x4[2 * t], f1 = x4[2 * t + 1];
            tmp[0] = f2bf(f0.x); tmp[1] = f2bf(f0.y); tmp[2] = f2bf(f0.z); tmp[3] = f2bf(f0.w);
            tmp[4] = f2bf(f1.x); tmp[5] = f2bf(f1.y); tmp[6] = f2bf(f1.z); tmp[7] = f2bf(f1.w);
        } else {
            const uint4* x4 = (const uint4*)((const ushort_t*)xraw + (size_t)m0 * 128);
            uint4 u = x4[t];
            __builtin_memcpy(tmp, &u, 16);
        }
        *reinterpret_cast<uint4*>(&sA[t * 8]) = *reinterpret_cast<uint4*>(tmp);
    }
    __syncthreads();
    int mr = lane & 15, quad = lane >> 4;
    int n0 = wave * 128;
    f32x4 acc[8];
#pragma unroll
    for (int ct = 0; ct < 8; ++ct) acc[ct] = {0.f, 0.f, 0.f, 0.f};
#pragma unroll
    for (int kk = 0; kk < 4; ++kk) {
        bf16x8 a = *reinterpret_cast<const bf16x8*>(&sA[mr * 128 + quad * 8 + kk * 32]);
#pragma unroll
        for (int ct = 0; ct < 8; ++ct) {
            bf16x8 bb = *reinterpret_cast<const bf16x8*>(
                &w1t[(size_t)(n0 + ct * 16 + mr) * 128 + quad * 8 + kk * 32]);
            acc[ct] = __builtin_amdgcn_mfma_f32_16x16x32_bf16(a, bb, acc[ct], 0, 0, 0);
        }
    }
    int col = lane & 15;
#pragma unroll
    for (int hh = 0; hh < 2; ++hh) {
        float Ss[4] = {0.f, 0.f, 0.f, 0.f}, Dd[4] = {0.f, 0.f, 0.f, 0.f};
#pragma unroll
        for (int c4 = 0; c4 < 4; ++c4) {
            int ct = hh * 4 + c4;
            int abscol = n0 + ct * 16 + col;
            float asv = prm[PO_AS1 + abscol];
            float adv = prm[PO_AD1 + abscol];
            float ps[4], pd[4];
#pragma unroll
            for (int r = 0; r < 4; ++r) {
                h1[(size_t)(m0 + quad * 4 + r) * 512 + abscol] = f2fp8(acc[ct][r]);
                ps[r] = acc[ct][r] * asv;
                pd[r] = acc[ct][r] * adv;
            }
#pragma unroll
            for (int off = 1; off <= 8; off <<= 1) {
#pragma unroll
                for (int r = 0; r < 4; ++r) {
                    ps[r] += __shfl_xor(ps[r], off, 64);
                    pd[r] += __shfl_xor(pd[r], off, 64);
                }
            }
#pragma unroll
            for (int r = 0; r < 4; ++r) { Ss[r] += ps[r]; Dd[r] += pd[r]; }
        }
        if (col == 0) {
            int head = 2 * wave + hh;
#pragma unroll
            for (int r = 0; r < 4; ++r) {
                asrcf[(m0 + quad * 4 + r) * 8 + head] = Ss[r];
                adstf[(m0 + quad * 4 + r) * 8 + head] = Dd[r];
            }
        }
    }
}

// ---- single-kernel exclusive scan: block b covers nodes [b*256, b*256+256).
// Base offset computed by redundantly summing deg[0..b*256) (L2-hot, coalesced).
__global__ __launch_bounds__(256) void k_scan(const int* __restrict__ deg,
                                              int* __restrict__ rowptr,
                                              int* __restrict__ cursor, int N) {
    int b = blockIdx.x, t = threadIdx.x;
    int lane = t & 63, wv = t >> 6;
    __shared__ int ws[4], wt[4];
    __shared__ int sbase;
    int limit = b * 256;
    int partial = 0;
    for (int i = t; i < limit; i += 256) partial += deg[i];
#pragma unroll
    for (int off = 32; off; off >>= 1) partial += __shfl_xor(partial, off, 64);
    if (lane == 0) ws[wv] = partial;
    __syncthreads();
    if (t == 0) sbase = ws[0] + ws[1] + ws[2] + ws[3];
    __syncthreads();
    int base = sbase;
    int i = limit + t;
    int v = (i < N) ? deg[i] : 0;
    int inc = v;
#pragma unroll
    for (int off = 1; off < 64; off <<= 1) {
        int u = __shfl_up(inc, off, 64);
        if (lane >= off) inc += u;
    }
    if (lane == 63) wt[wv] = inc;
    __syncthreads();
    int woff = 0;
    for (int w = 0; w < 4; ++w) if (w < wv) woff += wt[w];
    int excl = base + woff + inc - v;
    if (i < N) { rowptr[i + 1] = excl + v; cursor[i] = excl; }
    if (i == 0) rowptr[0] = 0;
}

__global__ void k_scatter(const int* __restrict__ ei, int* __restrict__ cursor,
                          int* __restrict__ csr_src, int E, int Etot) {
    int e = blockIdx.x * 256 + threadIdx.x;
    if (e >= Etot) return;
    int src, dst;
    if (e < E) { src = ei[e]; dst = ei[E + e]; } else { src = dst = e - E; }
    int pos = atomicAdd(&cursor[dst], 1);
    csr_src[pos] = src;
}

// --- layer-1 softmax+agg+ELU+layer-2 linear&logits, WAVE PER NODE, fp8 gather ---
__global__ __launch_bounds__(256) void k_agg1(const uchar_t* __restrict__ h1,
                                              const float* __restrict__ asrcf,
                                              const float* __restrict__ adstf,
                                              const int* __restrict__ rowptr,
                                              const int* __restrict__ csr_src,
                                              const float* __restrict__ prm,
                                              float* __restrict__ h2,
                                              float* __restrict__ asrc2f,
                                              float* __restrict__ adst2f) {
    int n = blockIdx.x * 4 + (threadIdx.x >> 6);
    int lane = threadIdx.x & 63;
    int hh = lane >> 3;
    int cb = lane * 8;
    int start = rowptr[n], end = rowptr[n + 1];
    int deg = end - start;
    float adh = adstf[n * 8 + hh];
    float a0 = 0.f, a1 = 0.f, a2 = 0.f, a3 = 0.f, a4 = 0.f, a5 = 0.f, a6 = 0.f, a7 = 0.f;
    float den = 0.f;
    for (int base = 0; base < deg; base += 64) {
        int m = min(64, deg - base);
        int sIdx = csr_src[start + base + min(lane, m - 1)];
        for (int g = 0; g < m; g += 8) {
            int s[8]; float lo[8]; uint2 p[8];
#pragma unroll
            for (int j = 0; j < 8; ++j)
                s[j] = __shfl(sIdx, min(g + j, m - 1), 64);
#pragma unroll
            for (int j = 0; j < 8; ++j)
                lo[j] = asrcf[s[j] * 8 + hh];
#pragma unroll
            for (int j = 0; j < 8; ++j)
                p[j] = *reinterpret_cast<const uint2*>(&h1[(size_t)s[j] * 512 + cb]);
#pragma unroll
            for (int j = 0; j < 8; ++j) {
                float we = (g + j < m) ? __expf(leaky(lo[j] + adh)) : 0.f;
                den += we;
                f32x2 q0 = __builtin_amdgcn_cvt_pk_f32_fp8((int)p[j].x, false);
                f32x2 q1 = __builtin_amdgcn_cvt_pk_f32_fp8((int)p[j].x, true);
                f32x2 q2 = __builtin_amdgcn_cvt_pk_f32_fp8((int)p[j].y, false);
                f32x2 q3 = __builtin_amdgcn_cvt_pk_f32_fp8((int)p[j].y, true);
                a0 += we * q0.x; a1 += we * q0.y;
                a2 += we * q1.x; a3 += we * q1.y;
                a4 += we * q2.x; a5 += we * q2.y;
                a6 += we * q3.x; a7 += we * q3.y;
            }
        }
    }
    float inv = 1.f / (den + 1e-16f);
    float r[8] = {a0, a1, a2, a3, a4, a5, a6, a7};
    float p2[10];
#pragma unroll
    for (int c = 0; c < 10; ++c) p2[c] = 0.f;
#pragma unroll
    for (int j = 0; j < 8; ++j) {
        float rv = r[j] * inv + prm[PO_B1 + cb + j];
        rv = (rv > 0.f) ? rv : expm1f(rv);    // ELU
#pragma unroll
        for (int c = 0; c < 10; ++c)
            p2[c] += rv * prm[PO_W2 + (cb + j) * 10 + c];
    }
#pragma unroll
    for (int c = 0; c < 10; ++c)
#pragma unroll
        for (int off = 32; off; off >>= 1)
            p2[c] += __shfl_xor(p2[c], off, 64);
    if (lane == 0) {
        float as = 0.f, ad = 0.f;
#pragma unroll
        for (int c = 0; c < 10; ++c) {
            h2[n * 10 + c] = p2[c];
            as += p2[c] * prm[PO_AS2 + c];
            ad += p2[c] * prm[PO_AD2 + c];
        }
        asrc2f[n] = as; adst2f[n] = ad;
    }
}

// ------- layer-2 softmax + aggregation, single pass (wave per dst, 4/block) -------
__global__ __launch_bounds__(256) void k_agg2(const float* __restrict__ h2,
                                              const float* __restrict__ asrc2f,
                                              const float* __restrict__ adst2f,
                                              const int* __restrict__ rowptr,
                                              const int* __restrict__ csr_src,
                                              const float* __restrict__ prm,
                                              float* __restrict__ out2) {
    int n = blockIdx.x * 4 + (threadIdx.x >> 6);
    int l = threadIdx.x & 63;
    int start = rowptr[n], end = rowptr[n + 1];
    float adn = adst2f[n];
    float den = 0.f;
    float oc[10];
#pragma unroll
    for (int c = 0; c < 10; ++c) oc[c] = 0.f;
    int e = start + l;
    int s_cur = (e < end) ? csr_src[e] : 0;
    for (; e < end; ) {
        int e_next = e + 64;
        int s_next = (e_next < end) ? csr_src[e_next] : 0;
        float lo = asrc2f[s_cur];
        const float2* hp = reinterpret_cast<const float2*>(&h2[s_cur * 10]);
        float2 q0 = hp[0], q1 = hp[1], q2 = hp[2], q3 = hp[3], q4 = hp[4];
        float ee = __expf(leaky(lo + adn));
        den += ee;
        oc[0] += ee * q0.x; oc[1] += ee * q0.y;
        oc[2] += ee * q1.x; oc[3] += ee * q1.y;
        oc[4] += ee * q2.x; oc[5] += ee * q2.y;
        oc[6] += ee * q3.x; oc[7] += ee * q3.y;
        oc[8] += ee * q4.x; oc[9] += ee * q4.y;
        e = e_next; s_cur = s_next;
    }
#pragma unroll
    for (int off = 32; off; off >>= 1) {
        den += __shfl_xor(den, off, 64);
#pragma unroll
        for (int c = 0; c < 10; ++c) oc[c] += __shfl_xor(oc[c], off, 64);
    }
    if (l == 0) {
        float inv = 1.f / (den + 1e-16f);
        for (int c = 0; c < 10; ++c) out2[n * 10 + c] = oc[c] * inv + prm[PO_B2 + c];
    }
}

// ---------------- per-graph mean pool ----------------
__global__ __launch_bounds__(256) void k_pool(const float* __restrict__ out2,
                                              const int* __restrict__ batch,
                                              const void* __restrict__ x,
                                              void* __restrict__ dout, int N) {
    bool isf = detect_fp32_local((const ushort_t*)x);
    int g = blockIdx.x, t = threadIdx.x;
    __shared__ int s_lo, s_hi;
    __shared__ float sm[256];
    if (t == 0) {
        int lo = 0, hi = N;
        while (lo < hi) { int mid = (lo + hi) >> 1; if (batch[mid] < g) lo = mid + 1; else hi = mid; }
        s_lo = lo;
        int lo2 = lo, hi2 = N;
        while (lo2 < hi2) { int mid = (lo2 + hi2) >> 1; if (batch[mid] < g + 1) lo2 = mid + 1; else hi2 = mid; }
        s_hi = lo2;
    }
    __syncthreads();
    int lo = s_lo, hi = s_hi;
    float acc[10];
#pragma unroll
    for (int c = 0; c < 10; ++c) acc[c] = 0.f;
    for (int i = lo + t; i < hi; i += 256)
#pragma unroll
        for (int c = 0; c < 10; ++c) acc[c] += out2[i * 10 + c];
    float cnt = (float)((hi - lo) > 0 ? (hi - lo) : 1);
    for (int c = 0; c < 10; ++c) {
        sm[t] = acc[c]; __syncthreads();
        for (int off = 128; off; off >>= 1) {
            if (t < off) sm[t] += sm[t + off];
            __syncthreads();
        }
        if (t == 0) {
            float r = sm[0] / cnt;
            if (isf) ((float*)dout)[g * 10 + c] = r;
            else     ((ushort_t*)dout)[g * 10 + c] = f2bf(r);
        }
        __syncthreads();
    }
}

extern "C" void kernel_launch(void* const* d_in, const int* in_sizes, int n_in,
                              void* d_out, int out_size, void* d_ws, size_t ws_size,
                              hipStream_t stream) {
    const void* x   = d_in[0];
    const int* ei   = (const int*)d_in[1];
    const int* batch= (const int*)d_in[2];
    const void* W1  = d_in[3];
    const void* as1 = d_in[4];
    const void* ad1 = d_in[5];
    const void* b1  = d_in[6];
    const void* W2  = d_in[7];
    const void* as2 = d_in[8];
    const void* ad2 = d_in[9];
    const void* b2  = d_in[10];

    constexpr int N = 20000, E = 320000, Etot = E + N;
    constexpr int histBlocks = (Etot + 255) / 256;

    char* p = (char*)d_ws;
    auto alloc = [&](size_t bytes) {
        char* r = p; p += (bytes + 255) & ~(size_t)255; return r;
    };
    float* prm      = (float*)alloc((size_t)PTOT * 4);
    ushort_t* w1t   = (ushort_t*)alloc(512 * 128 * 2);
    uchar_t* h1     = (uchar_t*)alloc((size_t)N * 512);           // 10.24 MB fp8
    float* asrc1f   = (float*)alloc((size_t)N * 8 * 4);
    float* adst1f   = (float*)alloc((size_t)N * 8 * 4);
    float* asrc2f   = (float*)alloc((size_t)N * 4);
    float* adst2f   = (float*)alloc((size_t)N * 4);
    float* h2       = (float*)alloc((size_t)N * 10 * 4);
    float* out2     = (float*)alloc((size_t)N * 10 * 4);
    int* deg        = (int*)alloc((size_t)N * 4);
    int* rowptr     = (int*)alloc((size_t)(N + 1) * 4);
    int* cursor     = (int*)alloc((size_t)N * 4);
    int* csr_src    = (int*)alloc((size_t)Etot * 4);

    k_prep<<<362, 256, 0, stream>>>(x, W1, as1, ad1, b1, W2, as2, ad2, b2,
                                    w1t, prm, deg, N);
    k_gemm_hist<<<1250 + histBlocks, 256, 0, stream>>>(x, w1t, prm, ei, h1,
                                                       asrc1f, adst1f, deg, E, Etot);
    k_scan<<<(N + 255) / 256, 256, 0, stream>>>(deg, rowptr, cursor, N);
    k_scatter<<<histBlocks, 256, 0, stream>>>(ei, cursor, csr_src, E, Etot);
    k_agg1<<<N / 4, 256, 0, stream>>>(h1, asrc1f, adst1f, rowptr, csr_src, prm,
                                      h2, asrc2f, adst2f);
    k_agg2<<<N / 4, 256, 0, stream>>>(h2, asrc2f, adst2f, rowptr, csr_src, prm, out2);
    k_pool<<<64, 256, 0, stream>>>(out2, batch, x, d_out, N);
}

// Round 13
// 256.839 us; speedup vs baseline: 4.7199x; 1.0325x over previous
//
#include <hip/hip_runtime.h>
#include <hip/hip_bf16.h>

typedef unsigned short ushort_t;
typedef unsigned int uint_t;
typedef unsigned char uchar_t;

typedef __attribute__((ext_vector_type(8))) short bf16x8;
typedef __attribute__((ext_vector_type(4))) float f32x4;
typedef __attribute__((ext_vector_type(2))) float f32x2;

__device__ __forceinline__ float bf2f(ushort_t u) {
    union { uint_t i; float f; } v; v.i = ((uint_t)u) << 16; return v.f;
}
__device__ __forceinline__ ushort_t f2bf(float f) {
    __hip_bfloat16 h = __float2bfloat16(f);
    ushort_t u; __builtin_memcpy(&u, &h, 2); return u;
}
__device__ __forceinline__ uchar_t f2fp8(float v) {
    int p = __builtin_amdgcn_cvt_pk_fp8_f32(v, v, 0, false);
    return (uchar_t)(p & 0xff);
}
__device__ __forceinline__ float leaky(float v) { return (v > 0.f) ? v : 0.2f * v; }

#define PO_AS1 0
#define PO_AD1 512
#define PO_B1  1024
#define PO_W2  1536
#define PO_AS2 6656
#define PO_AD2 6666
#define PO_B2  6676
#define PTOT   6686

// block-local fp32-vs-bf16 probe on x (first 4096 ushorts). Only used in k_prep;
// other kernels read the published flag (saves 4KB reads + 2 barriers per block).
__device__ __forceinline__ bool detect_fp32_local(const ushort_t* __restrict__ xa) {
    __shared__ int cnt;
    if (threadIdx.x == 0) cnt = 0;
    __syncthreads();
    int bad = 0;
    for (int i = threadIdx.x; i < 4096; i += 256) {
        float v = bf2f(xa[i]);
        if (!(fabsf(v) < 1e4f)) bad++;
    }
    if (bad) atomicAdd(&cnt, bad);
    __syncthreads();
    return cnt >= 16;
}

// ---- prep: W1 transpose + param normalize + deg zero + publish dtype flag ----
__global__ __launch_bounds__(256) void k_prep(const void* __restrict__ x,
                                              const void* __restrict__ W1,
                                              const void* as1, const void* ad1,
                                              const void* b1, const void* W2,
                                              const void* as2, const void* ad2,
                                              const void* b2,
                                              ushort_t* __restrict__ W1t,
                                              float* __restrict__ prm,
                                              int* __restrict__ deg,
                                              int* __restrict__ flag, int N) {
    int b = blockIdx.x, t = threadIdx.x;
    if (b < 283) {
        bool isf = detect_fp32_local((const ushort_t*)x);
        if (b == 0 && t == 0) *flag = isf ? 1 : 0;
        if (b < 256) {
            int idx = b * 256 + t;
            int n = idx & 511, k = idx >> 9;
            float v = isf ? ((const float*)W1)[k * 512 + n]
                          : bf2f(((const ushort_t*)W1)[k * 512 + n]);
            W1t[n * 128 + k] = f2bf(v);
        } else {
            int i = (b - 256) * 256 + t;
            if (i < PTOT) {
                const void* src; int off;
                if (i < 512)       { src = as1; off = i; }
                else if (i < 1024) { src = ad1; off = i - 512; }
                else if (i < 1536) { src = b1;  off = i - 1024; }
                else if (i < 6656) { src = W2;  off = i - 1536; }
                else if (i < 6666) { src = as2; off = i - 6656; }
                else if (i < 6676) { src = ad2; off = i - 6666; }
                else               { src = b2;  off = i - 6676; }
                prm[i] = isf ? ((const float*)src)[off] : bf2f(((const ushort_t*)src)[off]);
            }
        }
    } else {
        int i = (b - 283) * 256 + t;
        if (i < N) deg[i] = 0;
    }
}

// ------ fused GEMM1 (+logits) and degree histogram (independent halves) ------
__global__ __launch_bounds__(256) void k_gemm_hist(const void* __restrict__ xraw,
                                                   const ushort_t* __restrict__ w1t,
                                                   const float* __restrict__ prm,
                                                   const int* __restrict__ ei,
                                                   const int* __restrict__ flag,
                                                   uchar_t* __restrict__ h1,
                                                   float* __restrict__ asrcf,
                                                   float* __restrict__ adstf,
                                                   int* __restrict__ deg,
                                                   int E, int Etot) {
    int b = blockIdx.x, t = threadIdx.x;
    if (b >= 1250) {
        int e = (b - 1250) * 256 + t;
        if (e < Etot) {
            int dst = (e < E) ? ei[E + e] : (e - E);
            atomicAdd(&deg[dst], 1);
        }
        return;
    }
    int wave = t >> 6, lane = t & 63;
    int m0 = b * 16;
    bool isf = (*flag != 0);                 // uniform scalar read (published by k_prep)
    __shared__ ushort_t sA[16 * 128];
    {
        ushort_t tmp[8];
        if (isf) {
            const float4* x4 = (const float4*)((const float*)xraw + (size_t)m0 * 128);
            float4 f0 = x4[2 * t], f1 = x4[2 * t + 1];
            tmp[0] = f2bf(f0.x); tmp[1] = f2bf(f0.y); tmp[2] = f2bf(f0.z); tmp[3] = f2bf(f0.w);
            tmp[4] = f2bf(f1.x); tmp[5] = f2bf(f1.y); tmp[6] = f2bf(f1.z); tmp[7] = f2bf(f1.w);
        } else {
            const uint4* x4 = (const uint4*)((const ushort_t*)xraw + (size_t)m0 * 128);
            uint4 u = x4[t];
            __builtin_memcpy(tmp, &u, 16);
        }
        *reinterpret_cast<uint4*>(&sA[t * 8]) = *reinterpret_cast<uint4*>(tmp);
    }
    __syncthreads();
    int mr = lane & 15, quad = lane >> 4;
    int n0 = wave * 128;
    f32x4 acc[8];
#pragma unroll
    for (int ct = 0; ct < 8; ++ct) acc[ct] = {0.f, 0.f, 0.f, 0.f};
#pragma unroll
    for (int kk = 0; kk < 4; ++kk) {
        bf16x8 a = *reinterpret_cast<const bf16x8*>(&sA[mr * 128 + quad * 8 + kk * 32]);
#pragma unroll
        for (int ct = 0; ct < 8; ++ct) {
            bf16x8 bb = *reinterpret_cast<const bf16x8*>(
                &w1t[(size_t)(n0 + ct * 16 + mr) * 128 + quad * 8 + kk * 32]);
            acc[ct] = __builtin_amdgcn_mfma_f32_16x16x32_bf16(a, bb, acc[ct], 0, 0, 0);
        }
    }
    int col = lane & 15;
#pragma unroll
    for (int hh = 0; hh < 2; ++hh) {
        float Ss[4] = {0.f, 0.f, 0.f, 0.f}, Dd[4] = {0.f, 0.f, 0.f, 0.f};
#pragma unroll
        for (int c4 = 0; c4 < 4; ++c4) {
            int ct = hh * 4 + c4;
            int abscol = n0 + ct * 16 + col;
            float asv = prm[PO_AS1 + abscol];
            float adv = prm[PO_AD1 + abscol];
            float ps[4], pd[4];
#pragma unroll
            for (int r = 0; r < 4; ++r) {
                h1[(size_t)(m0 + quad * 4 + r) * 512 + abscol] = f2fp8(acc[ct][r]);
                ps[r] = acc[ct][r] * asv;
                pd[r] = acc[ct][r] * adv;
            }
#pragma unroll
            for (int off = 1; off <= 8; off <<= 1) {
#pragma unroll
                for (int r = 0; r < 4; ++r) {
                    ps[r] += __shfl_xor(ps[r], off, 64);
                    pd[r] += __shfl_xor(pd[r], off, 64);
                }
            }
#pragma unroll
            for (int r = 0; r < 4; ++r) { Ss[r] += ps[r]; Dd[r] += pd[r]; }
        }
        if (col == 0) {
            int head = 2 * wave + hh;
#pragma unroll
            for (int r = 0; r < 4; ++r) {
                asrcf[(m0 + quad * 4 + r) * 8 + head] = Ss[r];
                adstf[(m0 + quad * 4 + r) * 8 + head] = Dd[r];
            }
        }
    }
}

// ---- single-kernel exclusive scan ----
__global__ __launch_bounds__(256) void k_scan(const int* __restrict__ deg,
                                              int* __restrict__ rowptr,
                                              int* __restrict__ cursor, int N) {
    int b = blockIdx.x, t = threadIdx.x;
    int lane = t & 63, wv = t >> 6;
    __shared__ int ws[4], wt[4];
    __shared__ int sbase;
    int limit = b * 256;
    int partial = 0;
    for (int i = t; i < limit; i += 256) partial += deg[i];
#pragma unroll
    for (int off = 32; off; off >>= 1) partial += __shfl_xor(partial, off, 64);
    if (lane == 0) ws[wv] = partial;
    __syncthreads();
    if (t == 0) sbase = ws[0] + ws[1] + ws[2] + ws[3];
    __syncthreads();
    int base = sbase;
    int i = limit + t;
    int v = (i < N) ? deg[i] : 0;
    int inc = v;
#pragma unroll
    for (int off = 1; off < 64; off <<= 1) {
        int u = __shfl_up(inc, off, 64);
        if (lane >= off) inc += u;
    }
    if (lane == 63) wt[wv] = inc;
    __syncthreads();
    int woff = 0;
    for (int w = 0; w < 4; ++w) if (w < wv) woff += wt[w];
    int excl = base + woff + inc - v;
    if (i < N) { rowptr[i + 1] = excl + v; cursor[i] = excl; }
    if (i == 0) rowptr[0] = 0;
}

__global__ void k_scatter(const int* __restrict__ ei, int* __restrict__ cursor,
                          int* __restrict__ csr_src, int E, int Etot) {
    int e = blockIdx.x * 256 + threadIdx.x;
    if (e >= Etot) return;
    int src, dst;
    if (e < E) { src = ei[e]; dst = ei[E + e]; } else { src = dst = e - E; }
    int pos = atomicAdd(&cursor[dst], 1);
    csr_src[pos] = src;
}

// --- layer-1 softmax+agg+ELU+layer-2 linear&logits, WAVE PER NODE, fp8 gather ---
// h2 rows padded to 12 floats (48B, 16-aligned) for agg2's vector loads.
__global__ __launch_bounds__(256) void k_agg1(const uchar_t* __restrict__ h1,
                                              const float* __restrict__ asrcf,
                                              const float* __restrict__ adstf,
                                              const int* __restrict__ rowptr,
                                              const int* __restrict__ csr_src,
                                              const float* __restrict__ prm,
                                              float* __restrict__ h2,
                                              float* __restrict__ asrc2f,
                                              float* __restrict__ adst2f) {
    int n = blockIdx.x * 4 + (threadIdx.x >> 6);
    int lane = threadIdx.x & 63;
    int hh = lane >> 3;
    int cb = lane * 8;
    int start = rowptr[n], end = rowptr[n + 1];
    int deg = end - start;
    float adh = adstf[n * 8 + hh];
    float a0 = 0.f, a1 = 0.f, a2 = 0.f, a3 = 0.f, a4 = 0.f, a5 = 0.f, a6 = 0.f, a7 = 0.f;
    float den = 0.f;
    for (int base = 0; base < deg; base += 64) {
        int m = min(64, deg - base);
        int sIdx = csr_src[start + base + min(lane, m - 1)];
        for (int g = 0; g < m; g += 8) {
            int s[8]; float lo[8]; uint2 p[8];
#pragma unroll
            for (int j = 0; j < 8; ++j)
                s[j] = __shfl(sIdx, min(g + j, m - 1), 64);
#pragma unroll
            for (int j = 0; j < 8; ++j)
                lo[j] = asrcf[s[j] * 8 + hh];
#pragma unroll
            for (int j = 0; j < 8; ++j)
                p[j] = *reinterpret_cast<const uint2*>(&h1[(size_t)s[j] * 512 + cb]);
#pragma unroll
            for (int j = 0; j < 8; ++j) {
                float we = (g + j < m) ? __expf(leaky(lo[j] + adh)) : 0.f;
                den += we;
                f32x2 q0 = __builtin_amdgcn_cvt_pk_f32_fp8((int)p[j].x, false);
                f32x2 q1 = __builtin_amdgcn_cvt_pk_f32_fp8((int)p[j].x, true);
                f32x2 q2 = __builtin_amdgcn_cvt_pk_f32_fp8((int)p[j].y, false);
                f32x2 q3 = __builtin_amdgcn_cvt_pk_f32_fp8((int)p[j].y, true);
                a0 += we * q0.x; a1 += we * q0.y;
                a2 += we * q1.x; a3 += we * q1.y;
                a4 += we * q2.x; a5 += we * q2.y;
                a6 += we * q3.x; a7 += we * q3.y;
            }
        }
    }
    float inv = 1.f / (den + 1e-16f);
    float r[8] = {a0, a1, a2, a3, a4, a5, a6, a7};
    float p2[10];
#pragma unroll
    for (int c = 0; c < 10; ++c) p2[c] = 0.f;
#pragma unroll
    for (int j = 0; j < 8; ++j) {
        float rv = r[j] * inv + prm[PO_B1 + cb + j];
        rv = (rv > 0.f) ? rv : expm1f(rv);    // ELU
#pragma unroll
        for (int c = 0; c < 10; ++c)
            p2[c] += rv * prm[PO_W2 + (cb + j) * 10 + c];
    }
#pragma unroll
    for (int c = 0; c < 10; ++c)
#pragma unroll
        for (int off = 32; off; off >>= 1)
            p2[c] += __shfl_xor(p2[c], off, 64);
    if (lane == 0) {
        float as = 0.f, ad = 0.f;
#pragma unroll
        for (int c = 0; c < 10; ++c) {
            h2[n * 12 + c] = p2[c];
            as += p2[c] * prm[PO_AS2 + c];
            ad += p2[c] * prm[PO_AD2 + c];
        }
        asrc2f[n] = as; adst2f[n] = ad;
    }
}

// ------- layer-2 softmax + aggregation (wave per dst, 4/block; 48B h2 rows) -------
__global__ __launch_bounds__(256) void k_agg2(const float* __restrict__ h2,
                                              const float* __restrict__ asrc2f,
                                              const float* __restrict__ adst2f,
                                              const int* __restrict__ rowptr,
                                              const int* __restrict__ csr_src,
                                              const float* __restrict__ prm,
                                              float* __restrict__ out2) {
    int n = blockIdx.x * 4 + (threadIdx.x >> 6);
    int l = threadIdx.x & 63;
    int start = rowptr[n], end = rowptr[n + 1];
    float adn = adst2f[n];
    float den = 0.f;
    float oc[10];
#pragma unroll
    for (int c = 0; c < 10; ++c) oc[c] = 0.f;
    int e = start + l;
    int s_cur = (e < end) ? csr_src[e] : 0;
    for (; e < end; ) {
        int e_next = e + 64;
        int s_next = (e_next < end) ? csr_src[e_next] : 0;
        float lo = asrc2f[s_cur];
        const float4* hp = reinterpret_cast<const float4*>(&h2[s_cur * 12]);
        float4 q0 = hp[0], q1 = hp[1], q2 = hp[2];   // q2.z/.w are pad, unused
        float ee = __expf(leaky(lo + adn));
        den += ee;
        oc[0] += ee * q0.x; oc[1] += ee * q0.y; oc[2] += ee * q0.z; oc[3] += ee * q0.w;
        oc[4] += ee * q1.x; oc[5] += ee * q1.y; oc[6] += ee * q1.z; oc[7] += ee * q1.w;
        oc[8] += ee * q2.x; oc[9] += ee * q2.y;
        e = e_next; s_cur = s_next;
    }
#pragma unroll
    for (int off = 32; off; off >>= 1) {
        den += __shfl_xor(den, off, 64);
#pragma unroll
        for (int c = 0; c < 10; ++c) oc[c] += __shfl_xor(oc[c], off, 64);
    }
    if (l == 0) {
        float inv = 1.f / (den + 1e-16f);
        for (int c = 0; c < 10; ++c) out2[n * 10 + c] = oc[c] * inv + prm[PO_B2 + c];
    }
}

// ---------------- per-graph mean pool ----------------
__global__ __launch_bounds__(256) void k_pool(const float* __restrict__ out2,
                                              const int* __restrict__ batch,
                                              const int* __restrict__ flag,
                                              void* __restrict__ dout, int N) {
    bool isf = (*flag != 0);
    int g = blockIdx.x, t = threadIdx.x;
    __shared__ int s_lo, s_hi;
    __shared__ float sm[256];
    if (t == 0) {
        int lo = 0, hi = N;
        while (lo < hi) { int mid = (lo + hi) >> 1; if (batch[mid] < g) lo = mid + 1; else hi = mid; }
        s_lo = lo;
        int lo2 = lo, hi2 = N;
        while (lo2 < hi2) { int mid = (lo2 + hi2) >> 1; if (batch[mid] < g + 1) lo2 = mid + 1; else hi2 = mid; }
        s_hi = lo2;
    }
    __syncthreads();
    int lo = s_lo, hi = s_hi;
    float acc[10];
#pragma unroll
    for (int c = 0; c < 10; ++c) acc[c] = 0.f;
    for (int i = lo + t; i < hi; i += 256)
#pragma unroll
        for (int c = 0; c < 10; ++c) acc[c] += out2[i * 10 + c];
    float cnt = (float)((hi - lo) > 0 ? (hi - lo) : 1);
    for (int c = 0; c < 10; ++c) {
        sm[t] = acc[c]; __syncthreads();
        for (int off = 128; off; off >>= 1) {
            if (t < off) sm[t] += sm[t + off];
            __syncthreads();
        }
        if (t == 0) {
            float r = sm[0] / cnt;
            if (isf) ((float*)dout)[g * 10 + c] = r;
            else     ((ushort_t*)dout)[g * 10 + c] = f2bf(r);
        }
        __syncthreads();
    }
}

extern "C" void kernel_launch(void* const* d_in, const int* in_sizes, int n_in,
                              void* d_out, int out_size, void* d_ws, size_t ws_size,
                              hipStream_t stream) {
    const void* x   = d_in[0];
    const int* ei   = (const int*)d_in[1];
    const int* batch= (const int*)d_in[2];
    const void* W1  = d_in[3];
    const void* as1 = d_in[4];
    const void* ad1 = d_in[5];
    const void* b1  = d_in[6];
    const void* W2  = d_in[7];
    const void* as2 = d_in[8];
    const void* ad2 = d_in[9];
    const void* b2  = d_in[10];

    constexpr int N = 20000, E = 320000, Etot = E + N;
    constexpr int histBlocks = (Etot + 255) / 256;

    char* p = (char*)d_ws;
    auto alloc = [&](size_t bytes) {
        char* r = p; p += (bytes + 255) & ~(size_t)255; return r;
    };
    int* flag       = (int*)alloc(256);
    float* prm      = (float*)alloc((size_t)PTOT * 4);
    ushort_t* w1t   = (ushort_t*)alloc(512 * 128 * 2);
    uchar_t* h1     = (uchar_t*)alloc((size_t)N * 512);           // 10.24 MB fp8
    float* asrc1f   = (float*)alloc((size_t)N * 8 * 4);
    float* adst1f   = (float*)alloc((size_t)N * 8 * 4);
    float* asrc2f   = (float*)alloc((size_t)N * 4);
    float* adst2f   = (float*)alloc((size_t)N * 4);
    float* h2       = (float*)alloc((size_t)N * 12 * 4);          // 48B rows
    float* out2     = (float*)alloc((size_t)N * 10 * 4);
    int* deg        = (int*)alloc((size_t)N * 4);
    int* rowptr     = (int*)alloc((size_t)(N + 1) * 4);
    int* cursor     = (int*)alloc((size_t)N * 4);
    int* csr_src    = (int*)alloc((size_t)Etot * 4);

    k_prep<<<362, 256, 0, stream>>>(x, W1, as1, ad1, b1, W2, as2, ad2, b2,
                                    w1t, prm, deg, flag, N);
    k_gemm_hist<<<1250 + histBlocks, 256, 0, stream>>>(x, w1t, prm, ei, flag, h1,
                                                       asrc1f, adst1f, deg, E, Etot);
    k_scan<<<(N + 255) / 256, 256, 0, stream>>>(deg, rowptr, cursor, N);
    k_scatter<<<histBlocks, 256, 0, stream>>>(ei, cursor, csr_src, E, Etot);
    k_agg1<<<N / 4, 256, 0, stream>>>(h1, asrc1f, adst1f, rowptr, csr_src, prm,
                                      h2, asrc2f, adst2f);
    k_agg2<<<N / 4, 256, 0, stream>>>(h2, asrc2f, adst2f, rowptr, csr_src, prm, out2);
    k_pool<<<64, 256, 0, stream>>>(out2, batch, flag, d_out, N);
}

// Round 14
// 253.200 us; speedup vs baseline: 4.7878x; 1.0144x over previous
//
#include <hip/hip_runtime.h>
#include <hip/hip_bf16.h>

typedef unsigned short ushort_t;
typedef unsigned int uint_t;
typedef unsigned char uchar_t;

typedef __attribute__((ext_vector_type(8))) short bf16x8;
typedef __attribute__((ext_vector_type(4))) float f32x4;
typedef __attribute__((ext_vector_type(2))) float f32x2;

__device__ __forceinline__ float bf2f(ushort_t u) {
    union { uint_t i; float f; } v; v.i = ((uint_t)u) << 16; return v.f;
}
__device__ __forceinline__ ushort_t f2bf(float f) {
    __hip_bfloat16 h = __float2bfloat16(f);
    ushort_t u; __builtin_memcpy(&u, &h, 2); return u;
}
__device__ __forceinline__ uchar_t f2fp8(float v) {
    int p = __builtin_amdgcn_cvt_pk_fp8_f32(v, v, 0, false);
    return (uchar_t)(p & 0xff);
}
__device__ __forceinline__ float leaky(float v) { return (v > 0.f) ? v : 0.2f * v; }

#define PO_AS1 0
#define PO_AD1 512
#define PO_B1  1024
#define PO_W2  1536
#define PO_AS2 6656
#define PO_AD2 6666
#define PO_B2  6676
#define PTOT   6686

// block-local fp32-vs-bf16 probe on x (first 4096 ushorts). Only used in k_prep;
// other kernels read the published flag.
__device__ __forceinline__ bool detect_fp32_local(const ushort_t* __restrict__ xa) {
    __shared__ int cnt;
    if (threadIdx.x == 0) cnt = 0;
    __syncthreads();
    int bad = 0;
    for (int i = threadIdx.x; i < 4096; i += 256) {
        float v = bf2f(xa[i]);
        if (!(fabsf(v) < 1e4f)) bad++;
    }
    if (bad) atomicAdd(&cnt, bad);
    __syncthreads();
    return cnt >= 16;
}

// ---- prep: W1 transpose + param normalize + deg zero + publish dtype flag ----
__global__ __launch_bounds__(256) void k_prep(const void* __restrict__ x,
                                              const void* __restrict__ W1,
                                              const void* as1, const void* ad1,
                                              const void* b1, const void* W2,
                                              const void* as2, const void* ad2,
                                              const void* b2,
                                              ushort_t* __restrict__ W1t,
                                              float* __restrict__ prm,
                                              int* __restrict__ deg,
                                              int* __restrict__ flag, int N) {
    int b = blockIdx.x, t = threadIdx.x;
    if (b < 283) {
        bool isf = detect_fp32_local((const ushort_t*)x);
        if (b == 0 && t == 0) *flag = isf ? 1 : 0;
        if (b < 256) {
            int idx = b * 256 + t;
            int n = idx & 511, k = idx >> 9;
            float v = isf ? ((const float*)W1)[k * 512 + n]
                          : bf2f(((const ushort_t*)W1)[k * 512 + n]);
            W1t[n * 128 + k] = f2bf(v);
        } else {
            int i = (b - 256) * 256 + t;
            if (i < PTOT) {
                const void* src; int off;
                if (i < 512)       { src = as1; off = i; }
                else if (i < 1024) { src = ad1; off = i - 512; }
                else if (i < 1536) { src = b1;  off = i - 1024; }
                else if (i < 6656) { src = W2;  off = i - 1536; }
                else if (i < 6666) { src = as2; off = i - 6656; }
                else if (i < 6676) { src = ad2; off = i - 6666; }
                else               { src = b2;  off = i - 6676; }
                prm[i] = isf ? ((const float*)src)[off] : bf2f(((const ushort_t*)src)[off]);
            }
        }
    } else {
        int i = (b - 283) * 256 + t;
        if (i < N) deg[i] = 0;
    }
}

// ------ fused GEMM1 (+logits) and degree histogram (independent halves) ------
// Epilogue: per-head tile products accumulated per-lane FIRST (linear), then ONE
// 16-lane shuffle reduction per head — 64 shfl/wave instead of 256.
__global__ __launch_bounds__(256) void k_gemm_hist(const void* __restrict__ xraw,
                                                   const ushort_t* __restrict__ w1t,
                                                   const float* __restrict__ prm,
                                                   const int* __restrict__ ei,
                                                   const int* __restrict__ flag,
                                                   uchar_t* __restrict__ h1,
                                                   float* __restrict__ asrcf,
                                                   float* __restrict__ adstf,
                                                   int* __restrict__ deg,
                                                   int E, int Etot) {
    int b = blockIdx.x, t = threadIdx.x;
    if (b >= 1250) {
        int e = (b - 1250) * 256 + t;
        if (e < Etot) {
            int dst = (e < E) ? ei[E + e] : (e - E);
            atomicAdd(&deg[dst], 1);
        }
        return;
    }
    int wave = t >> 6, lane = t & 63;
    int m0 = b * 16;
    bool isf = (*flag != 0);
    __shared__ ushort_t sA[16 * 128];
    {
        ushort_t tmp[8];
        if (isf) {
            const float4* x4 = (const float4*)((const float*)xraw + (size_t)m0 * 128);
            float4 f0 = x4[2 * t], f1 = x4[2 * t + 1];
            tmp[0] = f2bf(f0.x); tmp[1] = f2bf(f0.y); tmp[2] = f2bf(f0.z); tmp[3] = f2bf(f0.w);
            tmp[4] = f2bf(f1.x); tmp[5] = f2bf(f1.y); tmp[6] = f2bf(f1.z); tmp[7] = f2bf(f1.w);
        } else {
            const uint4* x4 = (const uint4*)((const ushort_t*)xraw + (size_t)m0 * 128);
            uint4 u = x4[t];
            __builtin_memcpy(tmp, &u, 16);
        }
        *reinterpret_cast<uint4*>(&sA[t * 8]) = *reinterpret_cast<uint4*>(tmp);
    }
    __syncthreads();
    int mr = lane & 15, quad = lane >> 4;
    int n0 = wave * 128;
    f32x4 acc[8];
#pragma unroll
    for (int ct = 0; ct < 8; ++ct) acc[ct] = {0.f, 0.f, 0.f, 0.f};
#pragma unroll
    for (int kk = 0; kk < 4; ++kk) {
        bf16x8 a = *reinterpret_cast<const bf16x8*>(&sA[mr * 128 + quad * 8 + kk * 32]);
#pragma unroll
        for (int ct = 0; ct < 8; ++ct) {
            bf16x8 bb = *reinterpret_cast<const bf16x8*>(
                &w1t[(size_t)(n0 + ct * 16 + mr) * 128 + quad * 8 + kk * 32]);
            acc[ct] = __builtin_amdgcn_mfma_f32_16x16x32_bf16(a, bb, acc[ct], 0, 0, 0);
        }
    }
    int col = lane & 15;
#pragma unroll
    for (int hh = 0; hh < 2; ++hh) {
        float ps[4] = {0.f, 0.f, 0.f, 0.f}, pd[4] = {0.f, 0.f, 0.f, 0.f};
#pragma unroll
        for (int c4 = 0; c4 < 4; ++c4) {
            int ct = hh * 4 + c4;
            int abscol = n0 + ct * 16 + col;
            float asv = prm[PO_AS1 + abscol];
            float adv = prm[PO_AD1 + abscol];
#pragma unroll
            for (int r = 0; r < 4; ++r) {
                h1[(size_t)(m0 + quad * 4 + r) * 512 + abscol] = f2fp8(acc[ct][r]);
                ps[r] += acc[ct][r] * asv;
                pd[r] += acc[ct][r] * adv;
            }
        }
#pragma unroll
        for (int off = 1; off <= 8; off <<= 1) {
#pragma unroll
            for (int r = 0; r < 4; ++r) {
                ps[r] += __shfl_xor(ps[r], off, 64);
                pd[r] += __shfl_xor(pd[r], off, 64);
            }
        }
        if (col == 0) {
            int head = 2 * wave + hh;
#pragma unroll
            for (int r = 0; r < 4; ++r) {
                asrcf[(m0 + quad * 4 + r) * 8 + head] = ps[r];
                adstf[(m0 + quad * 4 + r) * 8 + head] = pd[r];
            }
        }
    }
}

// ---- single-kernel exclusive scan ----
__global__ __launch_bounds__(256) void k_scan(const int* __restrict__ deg,
                                              int* __restrict__ rowptr,
                                              int* __restrict__ cursor, int N) {
    int b = blockIdx.x, t = threadIdx.x;
    int lane = t & 63, wv = t >> 6;
    __shared__ int ws[4], wt[4];
    __shared__ int sbase;
    int limit = b * 256;
    int partial = 0;
    for (int i = t; i < limit; i += 256) partial += deg[i];
#pragma unroll
    for (int off = 32; off; off >>= 1) partial += __shfl_xor(partial, off, 64);
    if (lane == 0) ws[wv] = partial;
    __syncthreads();
    if (t == 0) sbase = ws[0] + ws[1] + ws[2] + ws[3];
    __syncthreads();
    int base = sbase;
    int i = limit + t;
    int v = (i < N) ? deg[i] : 0;
    int inc = v;
#pragma unroll
    for (int off = 1; off < 64; off <<= 1) {
        int u = __shfl_up(inc, off, 64);
        if (lane >= off) inc += u;
    }
    if (lane == 63) wt[wv] = inc;
    __syncthreads();
    int woff = 0;
    for (int w = 0; w < 4; ++w) if (w < wv) woff += wt[w];
    int excl = base + woff + inc - v;
    if (i < N) { rowptr[i + 1] = excl + v; cursor[i] = excl; }
    if (i == 0) rowptr[0] = 0;
}

__global__ void k_scatter(const int* __restrict__ ei, int* __restrict__ cursor,
                          int* __restrict__ csr_src, int E, int Etot) {
    int e = blockIdx.x * 256 + threadIdx.x;
    if (e >= Etot) return;
    int src, dst;
    if (e < E) { src = ei[e]; dst = ei[E + e]; } else { src = dst = e - E; }
    int pos = atomicAdd(&cursor[dst], 1);
    csr_src[pos] = src;
}

// --- layer-1 softmax+agg+ELU+layer-2 linear&logits, WAVE PER NODE, fp8 gather ---
__global__ __launch_bounds__(256) void k_agg1(const uchar_t* __restrict__ h1,
                                              const float* __restrict__ asrcf,
                                              const float* __restrict__ adstf,
                                              const int* __restrict__ rowptr,
                                              const int* __restrict__ csr_src,
                                              const float* __restrict__ prm,
                                              float* __restrict__ h2,
                                              float* __restrict__ asrc2f,
                                              float* __restrict__ adst2f) {
    int n = blockIdx.x * 4 + (threadIdx.x >> 6);
    int lane = threadIdx.x & 63;
    int hh = lane >> 3;
    int cb = lane * 8;
    int start = rowptr[n], end = rowptr[n + 1];
    int deg = end - start;
    float adh = adstf[n * 8 + hh];
    float a0 = 0.f, a1 = 0.f, a2 = 0.f, a3 = 0.f, a4 = 0.f, a5 = 0.f, a6 = 0.f, a7 = 0.f;
    float den = 0.f;
    for (int base = 0; base < deg; base += 64) {
        int m = min(64, deg - base);
        int sIdx = csr_src[start + base + min(lane, m - 1)];
        for (int g = 0; g < m; g += 8) {
            int s[8]; float lo[8]; uint2 p[8];
#pragma unroll
            for (int j = 0; j < 8; ++j)
                s[j] = __shfl(sIdx, min(g + j, m - 1), 64);
#pragma unroll
            for (int j = 0; j < 8; ++j)
                lo[j] = asrcf[s[j] * 8 + hh];
#pragma unroll
            for (int j = 0; j < 8; ++j)
                p[j] = *reinterpret_cast<const uint2*>(&h1[(size_t)s[j] * 512 + cb]);
#pragma unroll
            for (int j = 0; j < 8; ++j) {
                float we = (g + j < m) ? __expf(leaky(lo[j] + adh)) : 0.f;
                den += we;
                f32x2 q0 = __builtin_amdgcn_cvt_pk_f32_fp8((int)p[j].x, false);
                f32x2 q1 = __builtin_amdgcn_cvt_pk_f32_fp8((int)p[j].x, true);
                f32x2 q2 = __builtin_amdgcn_cvt_pk_f32_fp8((int)p[j].y, false);
                f32x2 q3 = __builtin_amdgcn_cvt_pk_f32_fp8((int)p[j].y, true);
                a0 += we * q0.x; a1 += we * q0.y;
                a2 += we * q1.x; a3 += we * q1.y;
                a4 += we * q2.x; a5 += we * q2.y;
                a6 += we * q3.x; a7 += we * q3.y;
            }
        }
    }
    float inv = 1.f / (den + 1e-16f);
    float r[8] = {a0, a1, a2, a3, a4, a5, a6, a7};
    float p2[10];
#pragma unroll
    for (int c = 0; c < 10; ++c) p2[c] = 0.f;
#pragma unroll
    for (int j = 0; j < 8; ++j) {
        float rv = r[j] * inv + prm[PO_B1 + cb + j];
        rv = (rv > 0.f) ? rv : expm1f(rv);    // ELU
#pragma unroll
        for (int c = 0; c < 10; ++c)
            p2[c] += rv * prm[PO_W2 + (cb + j) * 10 + c];
    }
#pragma unroll
    for (int c = 0; c < 10; ++c)
#pragma unroll
        for (int off = 32; off; off >>= 1)
            p2[c] += __shfl_xor(p2[c], off, 64);
    if (lane == 0) {
        float as = 0.f, ad = 0.f;
#pragma unroll
        for (int c = 0; c < 10; ++c) {
            h2[n * 12 + c] = p2[c];
            as += p2[c] * prm[PO_AS2 + c];
            ad += p2[c] * prm[PO_AD2 + c];
        }
        asrc2f[n] = as; adst2f[n] = ad;
    }
}

// ------- layer-2 softmax + aggregation (wave per dst, 4/block; 48B h2 rows) -------
__global__ __launch_bounds__(256) void k_agg2(const float* __restrict__ h2,
                                              const float* __restrict__ asrc2f,
                                              const float* __restrict__ adst2f,
                                              const int* __restrict__ rowptr,
                                              const int* __restrict__ csr_src,
                                              const float* __restrict__ prm,
                                              float* __restrict__ out2) {
    int n = blockIdx.x * 4 + (threadIdx.x >> 6);
    int l = threadIdx.x & 63;
    int start = rowptr[n], end = rowptr[n + 1];
    float adn = adst2f[n];
    float den = 0.f;
    float oc[10];
#pragma unroll
    for (int c = 0; c < 10; ++c) oc[c] = 0.f;
    int e = start + l;
    int s_cur = (e < end) ? csr_src[e] : 0;
    for (; e < end; ) {
        int e_next = e + 64;
        int s_next = (e_next < end) ? csr_src[e_next] : 0;
        float lo = asrc2f[s_cur];
        const float4* hp = reinterpret_cast<const float4*>(&h2[s_cur * 12]);
        float4 q0 = hp[0], q1 = hp[1], q2 = hp[2];
        float ee = __expf(leaky(lo + adn));
        den += ee;
        oc[0] += ee * q0.x; oc[1] += ee * q0.y; oc[2] += ee * q0.z; oc[3] += ee * q0.w;
        oc[4] += ee * q1.x; oc[5] += ee * q1.y; oc[6] += ee * q1.z; oc[7] += ee * q1.w;
        oc[8] += ee * q2.x; oc[9] += ee * q2.y;
        e = e_next; s_cur = s_next;
    }
#pragma unroll
    for (int off = 32; off; off >>= 1) {
        den += __shfl_xor(den, off, 64);
#pragma unroll
        for (int c = 0; c < 10; ++c) oc[c] += __shfl_xor(oc[c], off, 64);
    }
    if (l == 0) {
        float inv = 1.f / (den + 1e-16f);
        for (int c = 0; c < 10; ++c) out2[n * 10 + c] = oc[c] * inv + prm[PO_B2 + c];
    }
}

// ---------------- per-graph mean pool ----------------
__global__ __launch_bounds__(256) void k_pool(const float* __restrict__ out2,
                                              const int* __restrict__ batch,
                                              const int* __restrict__ flag,
                                              void* __restrict__ dout, int N) {
    bool isf = (*flag != 0);
    int g = blockIdx.x, t = threadIdx.x;
    __shared__ int s_lo, s_hi;
    __shared__ float sm[256];
    if (t == 0) {
        int lo = 0, hi = N;
        while (lo < hi) { int mid = (lo + hi) >> 1; if (batch[mid] < g) lo = mid + 1; else hi = mid; }
        s_lo = lo;
        int lo2 = lo, hi2 = N;
        while (lo2 < hi2) { int mid = (lo2 + hi2) >> 1; if (batch[mid] < g + 1) lo2 = mid + 1; else hi2 = mid; }
        s_hi = lo2;
    }
    __syncthreads();
    int lo = s_lo, hi = s_hi;
    float acc[10];
#pragma unroll
    for (int c = 0; c < 10; ++c) acc[c] = 0.f;
    for (int i = lo + t; i < hi; i += 256)
#pragma unroll
        for (int c = 0; c < 10; ++c) acc[c] += out2[i * 10 + c];
    float cnt = (float)((hi - lo) > 0 ? (hi - lo) : 1);
    for (int c = 0; c < 10; ++c) {
        sm[t] = acc[c]; __syncthreads();
        for (int off = 128; off; off >>= 1) {
            if (t < off) sm[t] += sm[t + off];
            __syncthreads();
        }
        if (t == 0) {
            float r = sm[0] / cnt;
            if (isf) ((float*)dout)[g * 10 + c] = r;
            else     ((ushort_t*)dout)[g * 10 + c] = f2bf(r);
        }
        __syncthreads();
    }
}

extern "C" void kernel_launch(void* const* d_in, const int* in_sizes, int n_in,
                              void* d_out, int out_size, void* d_ws, size_t ws_size,
                              hipStream_t stream) {
    const void* x   = d_in[0];
    const int* ei   = (const int*)d_in[1];
    const int* batch= (const int*)d_in[2];
    const void* W1  = d_in[3];
    const void* as1 = d_in[4];
    const void* ad1 = d_in[5];
    const void* b1  = d_in[6];
    const void* W2  = d_in[7];
    const void* as2 = d_in[8];
    const void* ad2 = d_in[9];
    const void* b2  = d_in[10];

    constexpr int N = 20000, E = 320000, Etot = E + N;
    constexpr int histBlocks = (Etot + 255) / 256;

    char* p = (char*)d_ws;
    auto alloc = [&](size_t bytes) {
        char* r = p; p += (bytes + 255) & ~(size_t)255; return r;
    };
    int* flag       = (int*)alloc(256);
    float* prm      = (float*)alloc((size_t)PTOT * 4);
    ushort_t* w1t   = (ushort_t*)alloc(512 * 128 * 2);
    uchar_t* h1     = (uchar_t*)alloc((size_t)N * 512);           // 10.24 MB fp8
    float* asrc1f   = (float*)alloc((size_t)N * 8 * 4);
    float* adst1f   = (float*)alloc((size_t)N * 8 * 4);
    float* asrc2f   = (float*)alloc((size_t)N * 4);
    float* adst2f   = (float*)alloc((size_t)N * 4);
    float* h2       = (float*)alloc((size_t)N * 12 * 4);          // 48B rows
    float* out2     = (float*)alloc((size_t)N * 10 * 4);
    int* deg        = (int*)alloc((size_t)N * 4);
    int* rowptr     = (int*)alloc((size_t)(N + 1) * 4);
    int* cursor     = (int*)alloc((size_t)N * 4);
    int* csr_src    = (int*)alloc((size_t)Etot * 4);

    k_prep<<<362, 256, 0, stream>>>(x, W1, as1, ad1, b1, W2, as2, ad2, b2,
                                    w1t, prm, deg, flag, N);
    k_gemm_hist<<<1250 + histBlocks, 256, 0, stream>>>(x, w1t, prm, ei, flag, h1,
                                                       asrc1f, adst1f, deg, E, Etot);
    k_scan<<<(N + 255) / 256, 256, 0, stream>>>(deg, rowptr, cursor, N);
    k_scatter<<<histBlocks, 256, 0, stream>>>(ei, cursor, csr_src, E, Etot);
    k_agg1<<<N / 4, 256, 0, stream>>>(h1, asrc1f, adst1f, rowptr, csr_src, prm,
                                      h2, asrc2f, adst2f);
    k_agg2<<<N / 4, 256, 0, stream>>>(h2, asrc2f, adst2f, rowptr, csr_src, prm, out2);
    k_pool<<<64, 256, 0, stream>>>(out2, batch, flag, d_out, N);
}